// Round 5
// baseline (459.179 us; speedup 1.0000x reference)
//
#include <hip/hip_runtime.h>

#define DD 8
#define HH 256
#define CH 8192          // edges per chunk in coarse/partition kernels
#define PAYBITS 17       // N <= 131072
#define PAYMASK 0x1FFFF

// ============================ CSR construction ==============================
// Bucketed counting sort: coarse bucket = node >> 9 (512 ids/bucket),
// fine bin = node & 511. No global atomics on node-sized arrays.

__global__ void k_coarse(const int* __restrict__ src, const int* __restrict__ dst,
                         int* __restrict__ gHistIn, int* __restrict__ gHistOut,
                         int NB, int E) {
    __shared__ int hIn[256], hOut[256];
    if (threadIdx.x < 256) { hIn[threadIdx.x] = 0; hOut[threadIdx.x] = 0; }
    __syncthreads();
    int lo = blockIdx.x * CH;
    int hi = min(lo + CH, E);
    for (int i = lo + threadIdx.x; i < hi; i += blockDim.x) {
        atomicAdd(&hIn[dst[i] >> 9], 1);
        atomicAdd(&hOut[src[i] >> 9], 1);
    }
    __syncthreads();
    if (threadIdx.x < NB) {
        int ci = hIn[threadIdx.x], co = hOut[threadIdx.x];
        if (ci) atomicAdd(&gHistIn[threadIdx.x], ci);
        if (co) atomicAdd(&gHistOut[threadIdx.x], co);
    }
}

__global__ void k_cscan(const int* __restrict__ gHistIn, const int* __restrict__ gHistOut,
                        int* __restrict__ cStartIn, int* __restrict__ cStartOut,
                        int* __restrict__ cCurIn, int* __restrict__ cCurOut,
                        int NB, int E) {
    __shared__ int s[256];
#pragma unroll
    for (int dir = 0; dir < 2; dir++) {
        const int* gh = dir ? gHistOut : gHistIn;
        int* cs = dir ? cStartOut : cStartIn;
        int* cc = dir ? cCurOut : cCurIn;
        int v = (threadIdx.x < NB) ? gh[threadIdx.x] : 0;
        s[threadIdx.x] = v;
        __syncthreads();
        for (int off = 1; off < 256; off <<= 1) {
            int t = (threadIdx.x >= off) ? s[threadIdx.x - off] : 0;
            __syncthreads();
            s[threadIdx.x] += t;
            __syncthreads();
        }
        if (threadIdx.x < NB) {
            int ex = s[threadIdx.x] - v;
            cs[threadIdx.x] = ex;
            cc[threadIdx.x] = ex;
        }
        if (threadIdx.x == 0) cs[NB] = E;
        __syncthreads();
    }
}

__global__ void k_partition(const int* __restrict__ key, const int* __restrict__ pay,
                            int* __restrict__ cCur, int* __restrict__ P,
                            int NB, int E) {
    __shared__ int h[256];
    if (threadIdx.x < 256) h[threadIdx.x] = 0;
    __syncthreads();
    int lo = blockIdx.x * CH;
    int hi = min(lo + CH, E);
    for (int i = lo + threadIdx.x; i < hi; i += blockDim.x)
        atomicAdd(&h[key[i] >> 9], 1);
    __syncthreads();
    if (threadIdx.x < NB) {
        int c = h[threadIdx.x];
        h[threadIdx.x] = c ? atomicAdd(&cCur[threadIdx.x], c) : 0;
    }
    __syncthreads();
    for (int i = lo + threadIdx.x; i < hi; i += blockDim.x) {
        int k = key[i];
        int pos = atomicAdd(&h[k >> 9], 1);
        P[pos] = ((k & 511) << PAYBITS) | pay[i];
    }
}

__launch_bounds__(512)
__global__ void k_fine(const int* __restrict__ cStart, const int* __restrict__ P,
                       int* __restrict__ start, int* __restrict__ csr, int N) {
    __shared__ int cnt[512], scn[512];
    int b = blockIdx.x;
    int lo = cStart[b], hi = cStart[b + 1];
    cnt[threadIdx.x] = 0;
    __syncthreads();
    for (int i = lo + threadIdx.x; i < hi; i += 512)
        atomicAdd(&cnt[P[i] >> PAYBITS], 1);
    __syncthreads();
    int own = cnt[threadIdx.x];
    scn[threadIdx.x] = own;
    __syncthreads();
    for (int off = 1; off < 512; off <<= 1) {
        int t = (threadIdx.x >= off) ? scn[threadIdx.x - off] : 0;
        __syncthreads();
        scn[threadIdx.x] += t;
        __syncthreads();
    }
    int base = lo + scn[threadIdx.x] - own;
    int node = (b << 9) + threadIdx.x;
    if (node < N) start[node] = base;
    cnt[threadIdx.x] = base;   // reuse as cursor
    __syncthreads();
    for (int i = lo + threadIdx.x; i < hi; i += 512) {
        int p = P[i];
        int pos = atomicAdd(&cnt[p >> PAYBITS], 1);
        csr[pos] = p & PAYMASK;
    }
}

// ============== weight transpose: W1t[j*8+d] = W1[d*256+j] ==================
__global__ void k_wt(const float* __restrict__ W1, float* __restrict__ W1t) {
    int i = blockIdx.x * blockDim.x + threadIdx.x;   // 2048 threads
    if (i < HH * DD) W1t[i] = W1[(i & 7) * HH + (i >> 3)];
}

// ===================== per-node prep (norms, masses, dHdP) ==================
__global__ void k_prep(const float* __restrict__ q, const float* __restrict__ p,
                       const float* __restrict__ M,
                       int* __restrict__ start_in, int* __restrict__ start_out,
                       float* __restrict__ a, float* __restrict__ b,
                       float* __restrict__ hmd, float* __restrict__ qn,
                       float* __restrict__ out, int N, int E) {
    int v = blockIdx.x * blockDim.x + threadIdx.x;
    if (blockIdx.x == 0 && threadIdx.x == 0) { start_in[N] = E; start_out[N] = E; }
    if (v >= N) return;
    int ei1 = (v + 1 < N) ? start_in[v + 1]  : E;
    int eo1 = (v + 1 < N) ? start_out[v + 1] : E;
    float din  = (float)(ei1 - start_in[v]);
    float dout = (float)(eo1 - start_out[v]);
    float av = 1.0f / sqrtf(dout > 0.f ? dout : 1.f);   // norm_src
    float bv = 1.0f / sqrtf(din  > 0.f ? din  : 1.f);   // norm_dst
    a[v] = av; b[v] = bv;
#pragma unroll
    for (int d = 0; d < DD; d++) {
        float m = M[(size_t)v * DD * DD + d * (DD + 1)];
        hmd[(size_t)v * 16 + 8 + d] = m;
        qn[(size_t)v * DD + d] = av * q[(size_t)v * DD + d];
        out[(size_t)v * 2 * DD + DD + d] = p[(size_t)v * DD + d] / m;  // dHdP
    }
}

// ================= atomic-free gathers: 8 lanes per node ====================

__global__ void k_gather8(const int* __restrict__ start, const int* __restrict__ csr,
                          const float* __restrict__ x, float* __restrict__ y, int N) {
    int t = blockIdx.x * blockDim.x + threadIdx.x;
    int v = t >> 3, d = t & 7;
    if (v >= N) return;
    int e0 = start[v], e1 = start[v + 1];
    float s = 0.f;
    int e = e0;
    for (; e + 3 < e1; e += 4) {
        int u0 = csr[e], u1 = csr[e + 1], u2 = csr[e + 2], u3 = csr[e + 3];
        float x0 = x[(size_t)u0 * DD + d], x1 = x[(size_t)u1 * DD + d];
        float x2 = x[(size_t)u2 * DD + d], x3 = x[(size_t)u3 * DD + d];
        s += (x0 + x1) + (x2 + x3);
    }
    for (; e < e1; e++) s += x[(size_t)csr[e] * DD + d];
    y[(size_t)v * DD + d] = s;
}

// h = b*AggIn(ya) + b2 + q, into hmd slots 0..7
__global__ void k_h_agg(const int* __restrict__ start, const int* __restrict__ csr,
                        const float* __restrict__ ya, const float* __restrict__ b,
                        const float* __restrict__ q, const float* __restrict__ b2,
                        float* __restrict__ hmd, int N) {
    int t = blockIdx.x * blockDim.x + threadIdx.x;
    int v = t >> 3, d = t & 7;
    if (v >= N) return;
    int e0 = start[v], e1 = start[v + 1];
    float s = 0.f;
    int e = e0;
    for (; e + 3 < e1; e += 4) {
        int u0 = csr[e], u1 = csr[e + 1], u2 = csr[e + 2], u3 = csr[e + 3];
        float x0 = ya[(size_t)u0 * DD + d], x1 = ya[(size_t)u1 * DD + d];
        float x2 = ya[(size_t)u2 * DD + d], x3 = ya[(size_t)u3 * DD + d];
        s += (x0 + x1) + (x2 + x3);
    }
    for (; e < e1; e++) s += ya[(size_t)csr[e] * DD + d];
    hmd[(size_t)v * 16 + d] = fmaf(b[v], s, b2[d] + q[(size_t)v * DD + d]);
}

// gravity gradient wrt h, symmetric per-node form, interleaved hmd reads
__global__ void k_gh(const int* __restrict__ start_in, const int* __restrict__ csr_in,
                     const int* __restrict__ start_out, const int* __restrict__ csr_out,
                     const float* __restrict__ hmd,
                     const float* __restrict__ b, const float* __restrict__ grav,
                     float* __restrict__ gh, float* __restrict__ bgh, int N) {
    int t = blockIdx.x * blockDim.x + threadIdx.x;
    int v = t >> 3, d = t & 7;
    if (v >= N) return;
    float hv = hmd[(size_t)v * 16 + d];
    float mv = hmd[(size_t)v * 16 + 8 + d];
    float coef = -0.5f * grav[0];
    float acc = 0.f;
#pragma unroll
    for (int dir = 0; dir < 2; dir++) {
        const int* start = dir ? start_out : start_in;
        const int* csr   = dir ? csr_out   : csr_in;
        int e1 = start[v + 1];
        int e = start[v];
        for (; e + 3 < e1; e += 4) {
            int u0 = csr[e], u1 = csr[e + 1], u2 = csr[e + 2], u3 = csr[e + 3];
            float h0 = hmd[(size_t)u0 * 16 + d], m0 = hmd[(size_t)u0 * 16 + 8 + d];
            float h1 = hmd[(size_t)u1 * 16 + d], m1 = hmd[(size_t)u1 * 16 + 8 + d];
            float h2 = hmd[(size_t)u2 * 16 + d], m2 = hmd[(size_t)u2 * 16 + 8 + d];
            float h3 = hmd[(size_t)u3 * 16 + d], m3 = hmd[(size_t)u3 * 16 + 8 + d];
            float d0 = hv - h0, d1 = hv - h1, d2 = hv - h2, d3 = hv - h3;
            float e20 = d0 * d0, e21 = d1 * d1, e22 = d2 * d2, e23 = d3 * d3;
            float S0 = mv * m0, S1 = mv * m1, S2 = mv * m2, S3 = mv * m3;
            e20 += __shfl_xor(e20, 1); S0 += __shfl_xor(S0, 1);
            e21 += __shfl_xor(e21, 1); S1 += __shfl_xor(S1, 1);
            e22 += __shfl_xor(e22, 1); S2 += __shfl_xor(S2, 1);
            e23 += __shfl_xor(e23, 1); S3 += __shfl_xor(S3, 1);
            e20 += __shfl_xor(e20, 2); S0 += __shfl_xor(S0, 2);
            e21 += __shfl_xor(e21, 2); S1 += __shfl_xor(S1, 2);
            e22 += __shfl_xor(e22, 2); S2 += __shfl_xor(S2, 2);
            e23 += __shfl_xor(e23, 2); S3 += __shfl_xor(S3, 2);
            e20 += __shfl_xor(e20, 4); S0 += __shfl_xor(S0, 4);
            e21 += __shfl_xor(e21, 4); S1 += __shfl_xor(S1, 4);
            e22 += __shfl_xor(e22, 4); S2 += __shfl_xor(S2, 4);
            e23 += __shfl_xor(e23, 4); S3 += __shfl_xor(S3, 4);
            float c0 = coef * S0 / (e20 * sqrtf(e20));
            float c1 = coef * S1 / (e21 * sqrtf(e21));
            float c2 = coef * S2 / (e22 * sqrtf(e22));
            float c3 = coef * S3 / (e23 * sqrtf(e23));
            acc = fmaf(c0, d0, acc); acc = fmaf(c1, d1, acc);
            acc = fmaf(c2, d2, acc); acc = fmaf(c3, d3, acc);
        }
        for (; e < e1; e++) {
            int u = csr[e];
            float hu = hmd[(size_t)u * 16 + d];
            float mu = hmd[(size_t)u * 16 + 8 + d];
            float dif = hv - hu;
            float e2 = dif * dif;
            float S  = mv * mu;
            e2 += __shfl_xor(e2, 1); S += __shfl_xor(S, 1);
            e2 += __shfl_xor(e2, 2); S += __shfl_xor(S, 2);
            e2 += __shfl_xor(e2, 4); S += __shfl_xor(S, 4);
            float c = coef * S / (e2 * sqrtf(e2));
            acc = fmaf(c, dif, acc);
        }
    }
    gh[(size_t)v * DD + d] = acc;
    bgh[(size_t)v * DD + d] = b[v] * acc;
}

__global__ void k_out_agg(const int* __restrict__ start, const int* __restrict__ csr,
                          const float* __restrict__ gz1b, const float* __restrict__ gh,
                          const float* __restrict__ a, float* __restrict__ out, int N) {
    int t = blockIdx.x * blockDim.x + threadIdx.x;
    int v = t >> 3, d = t & 7;
    if (v >= N) return;
    int e0 = start[v], e1 = start[v + 1];
    float s = 0.f;
    int e = e0;
    for (; e + 3 < e1; e += 4) {
        int u0 = csr[e], u1 = csr[e + 1], u2 = csr[e + 2], u3 = csr[e + 3];
        float x0 = gz1b[(size_t)u0 * DD + d], x1 = gz1b[(size_t)u1 * DD + d];
        float x2 = gz1b[(size_t)u2 * DD + d], x3 = gz1b[(size_t)u3 * DD + d];
        s += (x0 + x1) + (x2 + x3);
    }
    for (; e < e1; e++) s += gz1b[(size_t)csr[e] * DD + d];
    out[(size_t)v * 2 * DD + d] = fmaf(a[v], s, gh[(size_t)v * DD + d]);
}

// ================= MLP kernels: 8 threads per node ==========================
// Lane l handles hidden units j = 8c+l (c=0..31). Weight rows (32B) read from
// global: 8 consecutive j across lanes -> 256B coalesced, L1-resident (8KB).
// Cross-lane feature reduce: 24-shfl butterfly + static cndmask select.

__launch_bounds__(256)
__global__ void k_mlp_fwd(const float* __restrict__ agg1, const float* __restrict__ a,
                          const float* __restrict__ b,
                          const float* __restrict__ W1t, const float* __restrict__ b1,
                          const float* __restrict__ W2,
                          float* __restrict__ ya, int N) {
    int t = blockIdx.x * blockDim.x + threadIdx.x;
    int v = t >> 3, l = t & 7;
    if (v >= N) return;
    float bv = b[v];
    const float4* zp = (const float4*)(agg1 + (size_t)v * DD);
    float4 za = zp[0], zb = zp[1];
    float z[DD] = { bv * za.x, bv * za.y, bv * za.z, bv * za.w,
                    bv * zb.x, bv * zb.y, bv * zb.z, bv * zb.w };
    float acc[DD] = {0.f, 0.f, 0.f, 0.f, 0.f, 0.f, 0.f, 0.f};
    for (int c = 0; c < HH / DD; c++) {
        int j = (c << 3) | l;
        const float4* w1r = (const float4*)(W1t + j * DD);
        const float4* w2r = (const float4*)(W2  + j * DD);
        float4 wa = w1r[0], wb = w1r[1];
        float u = b1[j];
        u = fmaf(z[0], wa.x, u); u = fmaf(z[1], wa.y, u);
        u = fmaf(z[2], wa.z, u); u = fmaf(z[3], wa.w, u);
        u = fmaf(z[4], wb.x, u); u = fmaf(z[5], wb.y, u);
        u = fmaf(z[6], wb.z, u); u = fmaf(z[7], wb.w, u);
        float hh = fmaxf(u, 0.f);
        float4 va = w2r[0], vb = w2r[1];
        acc[0] = fmaf(hh, va.x, acc[0]); acc[1] = fmaf(hh, va.y, acc[1]);
        acc[2] = fmaf(hh, va.z, acc[2]); acc[3] = fmaf(hh, va.w, acc[3]);
        acc[4] = fmaf(hh, vb.x, acc[4]); acc[5] = fmaf(hh, vb.y, acc[5]);
        acc[6] = fmaf(hh, vb.z, acc[6]); acc[7] = fmaf(hh, vb.w, acc[7]);
    }
#pragma unroll
    for (int m = 1; m < 8; m <<= 1)
#pragma unroll
        for (int k = 0; k < DD; k++) acc[k] += __shfl_xor(acc[k], m);
    float yl = acc[0];
#pragma unroll
    for (int k = 1; k < DD; k++) yl = (l == k) ? acc[k] : yl;
    ya[(size_t)v * DD + l] = a[v] * yl;
}

__launch_bounds__(256)
__global__ void k_mlp_bwd(const float* __restrict__ gq2, const float* __restrict__ agg1,
                          const float* __restrict__ a, const float* __restrict__ b,
                          const float* __restrict__ W1t, const float* __restrict__ b1,
                          const float* __restrict__ W2,
                          float* __restrict__ gz1b, int N) {
    int t = blockIdx.x * blockDim.x + threadIdx.x;
    int v = t >> 3, l = t & 7;
    if (v >= N) return;
    float bv = b[v], av = a[v];
    const float4* zp = (const float4*)(agg1 + (size_t)v * DD);
    float4 za = zp[0], zb = zp[1];
    float z[DD] = { bv * za.x, bv * za.y, bv * za.z, bv * za.w,
                    bv * zb.x, bv * zb.y, bv * zb.z, bv * zb.w };
    const float4* gp = (const float4*)(gq2 + (size_t)v * DD);
    float4 ga = gp[0], gb = gp[1];
    float gq[DD] = { ga.x, ga.y, ga.z, ga.w, gb.x, gb.y, gb.z, gb.w };
    float gz[DD] = {0.f, 0.f, 0.f, 0.f, 0.f, 0.f, 0.f, 0.f};
    for (int c = 0; c < HH / DD; c++) {
        int j = (c << 3) | l;
        const float4* w1r = (const float4*)(W1t + j * DD);
        const float4* w2r = (const float4*)(W2  + j * DD);
        float4 wa = w1r[0], wb = w1r[1];
        float u = b1[j];
        u = fmaf(z[0], wa.x, u); u = fmaf(z[1], wa.y, u);
        u = fmaf(z[2], wa.z, u); u = fmaf(z[3], wa.w, u);
        u = fmaf(z[4], wb.x, u); u = fmaf(z[5], wb.y, u);
        u = fmaf(z[6], wb.z, u); u = fmaf(z[7], wb.w, u);
        float4 va = w2r[0], vb = w2r[1];
        float g = gq[0] * va.x + gq[1] * va.y + gq[2] * va.z + gq[3] * va.w
                + gq[4] * vb.x + gq[5] * vb.y + gq[6] * vb.z + gq[7] * vb.w;
        g = (u > 0.f) ? av * g : 0.f;
        gz[0] = fmaf(g, wa.x, gz[0]); gz[1] = fmaf(g, wa.y, gz[1]);
        gz[2] = fmaf(g, wa.z, gz[2]); gz[3] = fmaf(g, wa.w, gz[3]);
        gz[4] = fmaf(g, wb.x, gz[4]); gz[5] = fmaf(g, wb.y, gz[5]);
        gz[6] = fmaf(g, wb.z, gz[6]); gz[7] = fmaf(g, wb.w, gz[7]);
    }
#pragma unroll
    for (int m = 1; m < 8; m <<= 1)
#pragma unroll
        for (int k = 0; k < DD; k++) gz[k] += __shfl_xor(gz[k], m);
    float gl = gz[0];
#pragma unroll
    for (int k = 1; k < DD; k++) gl = (l == k) ? gz[k] : gl;
    gz1b[(size_t)v * DD + l] = bv * gl;
}

// ============================== launch =====================================

extern "C" void kernel_launch(void* const* d_in, const int* in_sizes, int n_in,
                              void* d_out, int out_size, void* d_ws, size_t ws_size,
                              hipStream_t stream) {
    const float* q    = (const float*)d_in[0];
    const float* p    = (const float*)d_in[1];
    const float* M    = (const float*)d_in[2];
    const int*   src  = (const int*)d_in[3];
    const int*   dst  = (const int*)d_in[4];
    const float* W1   = (const float*)d_in[5];
    const float* b1   = (const float*)d_in[6];
    const float* W2   = (const float*)d_in[7];
    const float* b2   = (const float*)d_in[8];
    const float* grav = (const float*)d_in[9];
    float* out = (float*)d_out;

    int N = in_sizes[0] / DD;
    int E = in_sizes[3];
    size_t n = (size_t)N;
    int NB = (N + 511) >> 9;   // coarse buckets (<=256 for N<=131072)

    // ---- float region (58N floats) ----
    float* ws   = (float*)d_ws;
    float* a_   = ws;             // N
    float* b_   = ws + n;         // N
    float* qn   = ws + 2  * n;    // 8N  (reused as gq2 after fwd gather)
    float* agg1 = ws + 10 * n;    // 8N  (kept live for bwd z-recompute)
    float* ya   = ws + 18 * n;    // 8N  (reused as gz1b)
    float* hmd  = ws + 26 * n;    // 16N (h slots 0..7, md slots 8..15)
    float* gh   = ws + 42 * n;    // 8N
    float* bgh  = ws + 50 * n;    // 8N
    float* gq2  = qn;
    float* gz1b = ya;

    // ---- int region ----
    int* iw        = (int*)(ws + 58 * n);
    int* csr_in    = iw;                       // E
    int* csr_out   = iw + (size_t)E;           // E
    int* start_in  = iw + 2 * (size_t)E;       // N+1
    int* start_out = start_in + n + 1;         // N+1
    int* gHistIn   = start_out + n + 1;        // 256
    int* gHistOut  = gHistIn + 256;            // 256
    int* cStartIn  = gHistOut + 256;           // NB+1
    int* cStartOut = cStartIn + NB + 1;        // NB+1
    int* cCurIn    = cStartOut + NB + 1;       // NB
    int* cCurOut   = cCurIn + NB;              // NB
    int* iwEnd     = cCurOut + NB;
    float* W1t     = (float*)iwEnd;            // 2048 floats
    // partition scratch (E ints): alias gh/bgh float region (dead during CSR build)
    int* P = (E <= 16 * (long long)n) ? (int*)(ws + 42 * n) : (int*)(W1t + HH * DD);

    hipMemsetAsync(gHistIn, 0, 512 * sizeof(int), stream);

    const int tb = 256;
    int gbN = (N + tb - 1) / tb;
    int gb8 = (int)((8 * n + tb - 1) / tb);
    int gbC = (E + CH - 1) / CH;

    // CSR build (bucketed counting sort, both directions; P reused)
    k_coarse   <<<gbC, tb, 0, stream>>>(src, dst, gHistIn, gHistOut, NB, E);
    k_wt       <<<8, tb, 0, stream>>>(W1, W1t);
    k_cscan    <<<1, 256, 0, stream>>>(gHistIn, gHistOut, cStartIn, cStartOut,
                                       cCurIn, cCurOut, NB, E);
    k_partition<<<gbC, tb, 0, stream>>>(dst, src, cCurIn, P, NB, E);
    k_fine     <<<NB, 512, 0, stream>>>(cStartIn, P, start_in, csr_in, N);
    k_partition<<<gbC, tb, 0, stream>>>(src, dst, cCurOut, P, NB, E);
    k_fine     <<<NB, 512, 0, stream>>>(cStartOut, P, start_out, csr_out, N);
    k_prep     <<<gbN, tb, 0, stream>>>(q, p, M, start_in, start_out,
                                        a_, b_, hmd, qn, out, N, E);

    // forward: agg1 = AggIn(a ⊙ q); ya = a ⊙ (relu((b⊙agg1)@W1+b1)@W2)
    k_gather8  <<<gb8, tb, 0, stream>>>(start_in, csr_in, qn, agg1, N);
    k_mlp_fwd  <<<gb8, tb, 0, stream>>>(agg1, a_, b_, W1t, b1, W2, ya, N);
    // h = b ⊙ AggIn(ya) + b2 + q  (into hmd slots 0..7)
    k_h_agg    <<<gb8, tb, 0, stream>>>(start_in, csr_in, ya, b_, q, b2, hmd, N);
    // gravity gradient (symmetric per-node, interleaved hmd, unroll-4)
    k_gh       <<<gb8, tb, 0, stream>>>(start_in, csr_in, start_out, csr_out,
                                        hmd, b_, grav, gh, bgh, N);
    // gq2 = AggOut(bgh); gz1b = b ⊙ ((a⊙(gq2@W2^T) ⊙ relu'(u)) @ W1^T)
    k_gather8  <<<gb8, tb, 0, stream>>>(start_out, csr_out, bgh, gq2, N);
    k_mlp_bwd  <<<gb8, tb, 0, stream>>>(gq2, agg1, a_, b_, W1t, b1, W2, gz1b, N);
    // dHdQ = gh + a ⊙ AggOut(gz1b)
    k_out_agg  <<<gb8, tb, 0, stream>>>(start_out, csr_out, gz1b, gh, a_, out, N);
}